// Round 5
// baseline (134.580 us; speedup 1.0000x reference)
//
#include <hip/hip_runtime.h>
#include <hip/hip_bf16.h>

// x[128][768][28][28] f32 -> per-(b,c) ascending-rank-392 of 784 values,
// then med[128][768] @ W[1000][768]^T + bias -> out[128][1000].

#define NROW 784
#define RANKK 392u
#define NWAVE 4   // rows (waves) per block

// ---------------- Kernel 1: per-wave exact select ----------------------------
// One 64-lane wave per row; no __syncthreads (wave-order LDS semantics).
// LDS budget per row (the bottleneck pipe): 1 zero + 16 hist atomics (scale-16
// binning -> ~1.6-way collisions, free per m136) + 1 hist read + ~14 ballot-
// compaction writes + 1 finisher read  ~= 33 wave-wide DS ops (was ~65).
// Finisher counts rank via readlane broadcasts (SALU) + float compares -> no
// LDS in the loop. Exact MSB-radix fallback retained for m>64 (any input).
__global__ __launch_bounds__(256, 8) void kth_select_kernel(
    const float* __restrict__ x, float* __restrict__ med) {
  __shared__ float cand[NWAVE][NROW];      // 12544 B
  __shared__ unsigned hist[NWAVE][64];     // 1024 B

  const int tid  = threadIdx.x;
  const int lane = tid & 63;
  const int w    = tid >> 6;
  const int row  = blockIdx.x * NWAVE + w;
  const float4* src4 = (const float4*)(x + (size_t)row * NROW);
  const unsigned long long ltm = (1ull << lane) - 1ull;

  // ---- load row: 196 float4 spread as {lane, 64+lane, 128+lane, 192+lane<4}
  float4 f0 = src4[lane];
  float4 f1 = src4[64 + lane];
  float4 f2 = src4[128 + lane];
  const bool v3 = (lane < 4);
  float4 f3 = make_float4(0.f, 0.f, 0.f, 0.f);
  if (v3) f3 = src4[192 + lane];

  const float vv[16] = {f0.x, f0.y, f0.z, f0.w, f1.x, f1.y, f1.z, f1.w,
                        f2.x, f2.y, f2.z, f2.w, f3.x, f3.y, f3.z, f3.w};

  // ---- zero wave-private histogram (single wave-wide DS write)
  hist[w][lane] = 0u;

  // ---- pass-1 histogram: bucket = clamp(floor(16v)+32, 0, 63), on the fly
#pragma unroll
  for (int j = 0; j < 12; ++j) {
    int bi = __float2int_rd(fmaf(vv[j], 16.f, 32.f));
    bi = min(max(bi, 0), 63);
    atomicAdd(&hist[w][bi], 1u);
  }
  if (v3) {
#pragma unroll
    for (int j = 12; j < 16; ++j) {
      int bi = __float2int_rd(fmaf(vv[j], 16.f, 32.f));
      bi = min(max(bi, 0), 63);
      atomicAdd(&hist[w][bi], 1u);
    }
  }

  // ---- scan histogram, find winning bucket D and rank r within it
  unsigned r = RANKK;
  unsigned m;
  int D;
  {
    const unsigned cnt = hist[w][lane];
    unsigned incl = cnt;
#pragma unroll
    for (int off = 1; off < 64; off <<= 1) {
      unsigned t = __shfl_up(incl, off, 64);
      if (lane >= off) incl += t;
    }
    const unsigned excl = incl - cnt;
    const bool hit = (r >= excl) && (r < incl);
    const unsigned long long hm = __ballot(hit);
    D = __ffsll(hm) - 1;                 // winning bucket == lane index
    r -= __shfl(excl, D, 64);
    m  = __shfl(cnt,  D, 64);
  }

  // ---- ballot compaction of winning-bucket floats (writes only, no atomics)
  {
    unsigned base = 0;
#pragma unroll
    for (int j = 0; j < 16; ++j) {
      const bool va = (j < 12) || v3;
      int bi = __float2int_rd(fmaf(vv[j], 16.f, 32.f));
      bi = min(max(bi, 0), 63);
      const bool match = va && (bi == D);
      const unsigned long long mk = __ballot(match);
      if (match) cand[w][base + (unsigned)__popcll(mk & ltm)] = vv[j];
      base += (unsigned)__popcll(mk);    // uniform -> SALU
    }
  }

  // ---- fallback: exact MSB 6-bit radix refinement (only if m > 64)
#pragma unroll 1
  for (int p = 0; p < 6; ++p) {
    if (m <= 64u) break;
    const int shift = (p < 5) ? (26 - 6 * p) : 0;
    hist[w][lane] = 0u;
    const int nch = (int)((m + 63u) >> 6);
    for (int c = 0; c < nch; ++c) {
      const int idx = (c << 6) + lane;
      if (idx < (int)m) {
        const unsigned b = __float_as_uint(cand[w][idx]);
        const unsigned key = (b & 0x80000000u) ? ~b : (b | 0x80000000u);
        atomicAdd(&hist[w][(key >> shift) & 63u], 1u);
      }
    }
    const unsigned cnt = hist[w][lane];
    unsigned incl = cnt;
#pragma unroll
    for (int off = 1; off < 64; off <<= 1) {
      unsigned t = __shfl_up(incl, off, 64);
      if (lane >= off) incl += t;
    }
    const unsigned excl = incl - cnt;
    const bool hit = (r >= excl) && (r < incl);
    const unsigned long long hm = __ballot(hit);
    const int Dp = __ffsll(hm) - 1;
    r -= __shfl(excl, Dp, 64);
    const unsigned m2 = __shfl(cnt, Dp, 64);
    // in-place ballot compact: each chunk fully read (one wave-wide ds_read)
    // before its writes; cumulative write index <= read index -> safe.
    unsigned base = 0;
    for (int c = 0; c < nch; ++c) {
      const int idx = (c << 6) + lane;
      const bool va = idx < (int)m;
      const float f = va ? cand[w][idx] : 0.f;
      const unsigned b = __float_as_uint(f);
      const unsigned key = (b & 0x80000000u) ? ~b : (b | 0x80000000u);
      const bool match = va && (((key >> shift) & 63u) == (unsigned)Dp);
      const unsigned long long mk = __ballot(match);
      if (match) cand[w][base + (unsigned)__popcll(mk & ltm)] = f;
      base += (unsigned)__popcll(mk);
    }
    m = m2;
  }

  // ---- finisher: one LDS read, then readlane(SALU)-broadcast count loop
  float sel = 0.f;
  bool win = false;
  if (m > 64u) {
    // exhausted all key bits -> remaining candidates identical
    sel = cand[w][0];
    win = (lane == 0);
  } else {
    const float myv = cand[w][lane];       // lanes >= m hold garbage; masked below
    unsigned cl = 0, ce = 0;
    for (int j = 0; j < (int)m; ++j) {     // j uniform -> readlane is SALU
      const float kj =
          __int_as_float(__builtin_amdgcn_readlane(__float_as_int(myv), j));
      cl += (kj < myv) ? 1u : 0u;
      ce += (kj == myv) ? 1u : 0u;
    }
    sel = myv;
    win = (lane < (int)m) && (cl <= r) && (r < cl + ce);
  }
  if (win) med[row] = sel;                 // duplicates write the same value
}

// ---------------- Kernel 2: small f32 GEMM out = med @ W^T + bias ------------
#define GO 32
#define GB 16
#define GK 64

__global__ __launch_bounds__(256) void gemm_kernel(
    const float* __restrict__ med, const float* __restrict__ W,
    const float* __restrict__ bias, float* __restrict__ out) {
  __shared__ float Ws[GK][GO + 1];  // [kc][ol], stride 33 -> conflict-free
  __shared__ float Ms[GB][GK];

  const int o0 = blockIdx.x * GO;
  const int b0 = blockIdx.y * GB;
  const int tid = threadIdx.x;
  const int to = tid & 31;
  const int tb = tid >> 5;   // 0..7, two b's each

  float acc0 = 0.f, acc1 = 0.f;

  for (int k0 = 0; k0 < 768; k0 += GK) {
#pragma unroll
    for (int idx = tid; idx < GO * GK; idx += 256) {
      const int kc = idx & (GK - 1);
      const int ol = idx >> 6;
      const int o = o0 + ol;
      Ws[kc][ol] = (o < 1000) ? W[(size_t)o * 768 + k0 + kc] : 0.f;
    }
#pragma unroll
    for (int idx = tid; idx < GB * GK; idx += 256) {
      const int kc = idx & (GK - 1);
      const int bl = idx >> 6;
      Ms[bl][kc] = med[(size_t)(b0 + bl) * 768 + k0 + kc];
    }
    __syncthreads();

    const int bl = tb * 2;
#pragma unroll
    for (int kk = 0; kk < GK; ++kk) {
      const float wv = Ws[kk][to];
      acc0 = fmaf(Ms[bl][kk], wv, acc0);
      acc1 = fmaf(Ms[bl + 1][kk], wv, acc1);
    }
    __syncthreads();
  }

  const int o = o0 + to;
  if (o < 1000) {
    const float bb = bias[o];
    const int b = b0 + tb * 2;
    out[(size_t)b * 1000 + o] = acc0 + bb;
    out[(size_t)(b + 1) * 1000 + o] = acc1 + bb;
  }
}

extern "C" void kernel_launch(void* const* d_in, const int* in_sizes, int n_in,
                              void* d_out, int out_size, void* d_ws, size_t ws_size,
                              hipStream_t stream) {
  const float* x = (const float*)d_in[0];    // [128,768,28,28]
  const float* W = (const float*)d_in[1];    // [1000,768]
  const float* b = (const float*)d_in[2];    // [1000]
  float* out = (float*)d_out;                // [128,1000]
  float* med = (float*)d_ws;                 // [128,768] scratch

  const int rows = 128 * 768;                // 98304
  kth_select_kernel<<<rows / NWAVE, 256, 0, stream>>>(x, med);

  dim3 grid((1000 + GO - 1) / GO, 128 / GB); // (32, 8)
  gemm_kernel<<<grid, 256, 0, stream>>>(med, W, b, out);
}